// Round 1
// baseline (107.923 us; speedup 1.0000x reference)
//
#include <hip/hip_runtime.h>

#define BATCH 16
#define SEQ   4096
#define DIM   64
#define WIN   512

constexpr int BM = 128;       // q rows per block
constexpr int BN = 64;        // keys per tile
constexpr int NTHREADS = 512; // 8 waves
constexpr int KS = DIM + 8;   // Ksh row stride (f16 elems)
constexpr int VS = BN + 4;    // Vsh row stride (f16 elems)
constexpr int OS = DIM + 4;   // Osh row stride (f32 elems)
constexpr int KBYTES   = BN * KS * 2;        // 9216
constexpr int VBYTES   = DIM * VS * 2;       // 8704
constexpr int BUFBYTES = KBYTES + VBYTES;    // 17920
constexpr int SMEMBYTES = 2 * BUFBYTES;      // 35840 >= epilogue BM*OS*4 = 34816

// fold softmax scale and log2(e) into Q so p = exp2(s - m)
constexpr float QSCALE  = 0.125f * 1.44269504088896340736f;
constexpr float MASKVAL = -3.0e38f;   // << m_run init (-1e30) so masked lanes give p=0
constexpr float DEFER_THR = 8.0f;     // T13: tolerate p up to 2^8 before rescaling O

typedef _Float16 f16x2 __attribute__((ext_vector_type(2)));
typedef _Float16 f16x4 __attribute__((ext_vector_type(4)));
typedef _Float16 f16x8 __attribute__((ext_vector_type(8)));
typedef float    f32x4 __attribute__((ext_vector_type(4)));

__device__ __forceinline__ f16x2 pk2(float a, float b) {
    return __builtin_bit_cast(f16x2, __builtin_amdgcn_cvt_pkrtz(a, b));
}

// stage two ADJACENT key rows (row2, row2+1): K rows as f16x4, V transposed as
// f16x2 pairs (the two rows are adjacent in Vsh's key dim -> one 4B store each)
__device__ __forceinline__ void stage_kv2(_Float16* __restrict__ Ksh, _Float16* __restrict__ Vsh,
                                          const float4& k0, const float4& k1,
                                          const float4& v0, const float4& v1,
                                          int row2, int c4) {
    union { f16x4 v; f16x2 h[2]; } uk;
    uk.h[0] = pk2(k0.x, k0.y);
    uk.h[1] = pk2(k0.z, k0.w);
    *(f16x4*)&Ksh[(row2 + 0) * KS + c4] = uk.v;
    uk.h[0] = pk2(k1.x, k1.y);
    uk.h[1] = pk2(k1.z, k1.w);
    *(f16x4*)&Ksh[(row2 + 1) * KS + c4] = uk.v;
    *(f16x2*)&Vsh[(c4 + 0) * VS + row2] = pk2(v0.x, v1.x);
    *(f16x2*)&Vsh[(c4 + 1) * VS + row2] = pk2(v0.y, v1.y);
    *(f16x2*)&Vsh[(c4 + 2) * VS + row2] = pk2(v0.z, v1.z);
    *(f16x2*)&Vsh[(c4 + 3) * VS + row2] = pk2(v0.w, v1.w);
}

__global__ __launch_bounds__(NTHREADS)
void swa_kernel(const float* __restrict__ qg, const float* __restrict__ kg,
                const float* __restrict__ vg, float* __restrict__ outg) {
    // double-buffered staging: buf[i] = { Ksh [BN][KS] f16 | Vsh [DIM][VS] f16 }
    // epilogue: Osh f32 [BM][OS] overlays both buffers
    __shared__ __align__(16) char smem[SMEMBYTES];
    float* Osh = (float*)smem;

    const int tid  = threadIdx.x;
    const int lane = tid & 63;
    const int wave = tid >> 6;     // 0..7
    const int lr   = lane & 15;
    const int quad = lane >> 4;

    const int b     = blockIdx.y;
    const int qblk  = blockIdx.x;
    const int qrow0 = qblk * BM;
    const int wr0   = qrow0 + wave * 16;
    const int q     = wr0 + lr;          // this lane's q column (S^T layout)

    const float* qb = qg + (size_t)b * SEQ * DIM;
    const float* kb = kg + (size_t)b * SEQ * DIM;
    const float* vb = vg + (size_t)b * SEQ * DIM;
    float*       ob = outg + (size_t)b * SEQ * DIM;

    // staging thread->slot map: two adjacent rows per thread
    const int row2 = (tid >> 4) * 2;      // 0,2,...,62
    const int c4   = (tid & 15) * 4;      // 0..60

    // ---- Q B-frags straight from global into registers ----
    const float* qp = qb + (size_t)q * DIM + quad * 8;
    const float4 a0 = *(const float4*)(qp + 0);
    const float4 a1 = *(const float4*)(qp + 4);
    const float4 a2 = *(const float4*)(qp + 32);
    const float4 a3 = *(const float4*)(qp + 36);
    union { f16x8 v; f16x2 h[4]; } uq0, uq1;
    uq0.h[0] = pk2(a0.x * QSCALE, a0.y * QSCALE);
    uq0.h[1] = pk2(a0.z * QSCALE, a0.w * QSCALE);
    uq0.h[2] = pk2(a1.x * QSCALE, a1.y * QSCALE);
    uq0.h[3] = pk2(a1.z * QSCALE, a1.w * QSCALE);
    uq1.h[0] = pk2(a2.x * QSCALE, a2.y * QSCALE);
    uq1.h[1] = pk2(a2.z * QSCALE, a2.w * QSCALE);
    uq1.h[2] = pk2(a3.x * QSCALE, a3.y * QSCALE);
    uq1.h[3] = pk2(a3.z * QSCALE, a3.w * QSCALE);
    const f16x8 qf0 = uq0.v, qf1 = uq1.v;

    f32x4 o[4];
    #pragma unroll
    for (int mi = 0; mi < 4; ++mi) o[mi] = (f32x4){0.f, 0.f, 0.f, 0.f};
    float m_run = -1e30f, l_run = 0.f;

    const int t0 = (qrow0 > (WIN - 1)) ? (qrow0 - (WIN - 1)) >> 6 : 0;
    const int t1 = (qrow0 + BM - 1) >> 6;

    // ---- prologue: stage tile t0 into buffer 0 ----
    {
        const size_t g0 = (size_t)(t0 * BN + row2) * DIM + c4;
        const float4 k0 = *(const float4*)&kb[g0];
        const float4 v0 = *(const float4*)&vb[g0];
        const float4 k1 = *(const float4*)&kb[g0 + DIM];
        const float4 v1 = *(const float4*)&vb[g0 + DIM];
        stage_kv2((_Float16*)smem, (_Float16*)(smem + KBYTES), k0, k1, v0, v1, row2, c4);
    }
    __syncthreads();

    for (int t = t0; t <= t1; ++t) {
        const int cb = (t - t0) & 1;
        const _Float16* Kc = (const _Float16*)(smem + cb * BUFBYTES);
        const _Float16* Vc = (const _Float16*)(smem + cb * BUFBYTES + KBYTES);
        const bool have_next = (t < t1);

        float4 kp0, kp1, vp0, vp1;
        if (have_next) {
            // issue next tile's global loads NOW; staged after compute so the
            // HBM/L2 latency hides under this tile's MFMA+softmax
            const size_t g0 = (size_t)((t + 1) * BN + row2) * DIM + c4;
            kp0 = *(const float4*)&kb[g0];
            vp0 = *(const float4*)&vb[g0];
            kp1 = *(const float4*)&kb[g0 + DIM];
            vp1 = *(const float4*)&vb[g0 + DIM];
        }

        const int kbase = t * BN;
        // wave-level skip: no key of this tile is inside this wave's window
        const bool active = (kbase + BN - 1 >= wr0 - (WIN - 1)) && (kbase <= wr0 + 15);
        if (active) {
            // ---- S^T = K * Q^T : 4 key m-tiles x 2 k-chunks of 32 ----
            f32x4 sc[4];
            __builtin_amdgcn_s_setprio(1);
            #pragma unroll
            for (int mt = 0; mt < 4; ++mt) {
                const f16x8 kf0 = *(const f16x8*)&Kc[(mt * 16 + lr) * KS + quad * 8];
                const f16x8 kf1 = *(const f16x8*)&Kc[(mt * 16 + lr) * KS + 32 + quad * 8];
                f32x4 s = (f32x4){0.f, 0.f, 0.f, 0.f};
                s = __builtin_amdgcn_mfma_f32_16x16x32_f16(kf0, qf0, s, 0, 0, 0);
                s = __builtin_amdgcn_mfma_f32_16x16x32_f16(kf1, qf1, s, 0, 0, 0);
                sc[mt] = s;
            }
            __builtin_amdgcn_s_setprio(0);

            // ---- mask only on window-edge tiles (wave-uniform branch) ----
            const bool edge = (kbase < wr0 + 15 - (WIN - 1)) || (kbase + BN - 1 > wr0);
            if (edge) {
                #pragma unroll
                for (int mt = 0; mt < 4; ++mt) {
                    #pragma unroll
                    for (int r = 0; r < 4; ++r) {
                        const int key = kbase + mt * 16 + quad * 4 + r;
                        sc[mt][r] = ((unsigned)(q - key) < (unsigned)WIN) ? sc[mt][r] : MASKVAL;
                    }
                }
            }

            // ---- row max: balanced tree (fuses to v_max3), then cross-quad ----
            const float pmA = fmaxf(fmaxf(sc[0][0], sc[0][1]), fmaxf(sc[0][2], sc[0][3]));
            const float pmB = fmaxf(fmaxf(sc[1][0], sc[1][1]), fmaxf(sc[1][2], sc[1][3]));
            const float pmC = fmaxf(fmaxf(sc[2][0], sc[2][1]), fmaxf(sc[2][2], sc[2][3]));
            const float pmD = fmaxf(fmaxf(sc[3][0], sc[3][1]), fmaxf(sc[3][2], sc[3][3]));
            float pm = fmaxf(fmaxf(pmA, pmB), fmaxf(pmC, pmD));
            pm = fmaxf(pm, __shfl_xor(pm, 16));
            pm = fmaxf(pm, __shfl_xor(pm, 32));

            // ---- T13 defer-rescale: only rescale when max grew by > THR ----
            if (__any(pm > m_run + DEFER_THR)) {
                const float mn    = fmaxf(m_run, pm);
                const float alpha = exp2f(m_run - mn);
                m_run = mn;
                l_run *= alpha;
                #pragma unroll
                for (int mi = 0; mi < 4; ++mi) o[mi] = o[mi] * alpha;
            }

            f16x4 pb[4];
            float ls = 0.f;
            #pragma unroll
            for (int nt = 0; nt < 4; ++nt) {
                const float p0 = exp2f(sc[nt][0] - m_run);
                const float p1 = exp2f(sc[nt][1] - m_run);
                const float p2 = exp2f(sc[nt][2] - m_run);
                const float p3 = exp2f(sc[nt][3] - m_run);
                ls += (p0 + p1) + (p2 + p3);
                union { f16x4 v; f16x2 h[2]; } up;
                up.h[0] = pk2(p0, p1);
                up.h[1] = pk2(p2, p3);
                pb[nt] = up.v;
            }
            l_run += ls;

            // ---- O^T += V^T * P^T : P^T (C-layout) is the B-operand of 16x16x16 ----
            __builtin_amdgcn_s_setprio(1);
            #pragma unroll
            for (int nt = 0; nt < 4; ++nt) {
                #pragma unroll
                for (int mi = 0; mi < 4; ++mi) {
                    const f16x4 vf = *(const f16x4*)&Vc[(mi * 16 + lr) * VS + nt * 16 + quad * 4];
                    o[mi] = __builtin_amdgcn_mfma_f32_16x16x16f16(vf, pb[nt], o[mi], 0, 0, 0);
                }
            }
            __builtin_amdgcn_s_setprio(0);
        }

        // ---- stage t+1 into the ALTERNATE buffer; one barrier per tile ----
        // (double buffer: writers touch buf[cb^1] while readers used buf[cb];
        //  the single __syncthreads orders write-visibility AND prevents any
        //  wave from re-entering buf[cb] as a writer before all reads done)
        if (have_next) {
            _Float16* Kn = (_Float16*)(smem + (cb ^ 1) * BUFBYTES);
            _Float16* Vn = (_Float16*)(smem + (cb ^ 1) * BUFBYTES + KBYTES);
            stage_kv2(Kn, Vn, kp0, kp1, vp0, vp1, row2, c4);
        }
        __syncthreads();
    }

    // ---- epilogue: l reduce across quads, normalize, transpose via LDS, store ----
    l_run += __shfl_xor(l_run, 16);
    l_run += __shfl_xor(l_run, 32);
    const float inv = 1.0f / l_run;

    float* Ow = Osh + wave * 16 * OS;   // per-wave private 16 x OS region
    #pragma unroll
    for (int mi = 0; mi < 4; ++mi) {
        float4 st;
        st.x = o[mi][0] * inv; st.y = o[mi][1] * inv;
        st.z = o[mi][2] * inv; st.w = o[mi][3] * inv;
        *(float4*)&Ow[lr * OS + mi * 16 + quad * 4] = st;
    }
    #pragma unroll
    for (int j = 0; j < 4; ++j) {
        const int qq = quad + 4 * j;
        const int d4 = lr * 4;
        const float4 vst = *(const float4*)&Ow[qq * OS + d4];
        *(float4*)&ob[(size_t)(wr0 + qq) * DIM + d4] = vst;
    }
}

extern "C" void kernel_launch(void* const* d_in, const int* in_sizes, int n_in,
                              void* d_out, int out_size, void* d_ws, size_t ws_size,
                              hipStream_t stream) {
    (void)in_sizes; (void)n_in; (void)out_size; (void)d_ws; (void)ws_size;
    const float* q = (const float*)d_in[0];
    const float* k = (const float*)d_in[1];
    const float* v = (const float*)d_in[2];
    float* out = (float*)d_out;
    dim3 grid(SEQ / BM, BATCH);
    swa_kernel<<<grid, dim3(NTHREADS), 0, stream>>>(q, k, v, out);
}

// Round 2
// 107.268 us; speedup vs baseline: 1.0061x; 1.0061x over previous
//
#include <hip/hip_runtime.h>

#define BATCH 16
#define SEQ   4096
#define DIM   64
#define WIN   512

constexpr int BM = 128;       // q rows per block
constexpr int BN = 64;        // keys per tile
constexpr int NTHREADS = 512; // 8 waves
constexpr int KS = DIM + 8;   // Ksh row stride (f16 elems)
constexpr int VS = BN + 4;    // Vsh row stride (f16 elems)
constexpr int OS = DIM + 4;   // Osh row stride (f32 elems)
constexpr int KBYTES   = BN * KS * 2;        // 9216
constexpr int VBYTES   = DIM * VS * 2;       // 8704
constexpr int BUFBYTES = KBYTES + VBYTES;    // 17920
constexpr int SMEMBYTES = 2 * BUFBYTES;      // 35840 >= epilogue BM*OS*4 = 34816

// fold softmax scale and log2(e) into Q so p = exp2(s - m)
constexpr float QSCALE  = 0.125f * 1.44269504088896340736f;
constexpr float MASKVAL = -3.0e38f;   // << m_run init (-1e30) so masked lanes give p=0
constexpr float DEFER_THR = 8.0f;     // T13: tolerate p up to 2^8 before rescaling O

typedef _Float16 f16x2 __attribute__((ext_vector_type(2)));
typedef _Float16 f16x4 __attribute__((ext_vector_type(4)));
typedef _Float16 f16x8 __attribute__((ext_vector_type(8)));
typedef float    f32x4 __attribute__((ext_vector_type(4)));

__device__ __forceinline__ f16x2 pk2(float a, float b) {
    return __builtin_bit_cast(f16x2, __builtin_amdgcn_cvt_pkrtz(a, b));
}

// stage two ADJACENT key rows (row2, row2+1): K rows as f16x4, V transposed as
// f16x2 pairs (the two rows are adjacent in Vsh's key dim -> one 4B store each)
__device__ __forceinline__ void stage_kv2(_Float16* __restrict__ Ksh, _Float16* __restrict__ Vsh,
                                          const float4& k0, const float4& k1,
                                          const float4& v0, const float4& v1,
                                          int row2, int c4) {
    union { f16x4 v; f16x2 h[2]; } uk;
    uk.h[0] = pk2(k0.x, k0.y);
    uk.h[1] = pk2(k0.z, k0.w);
    *(f16x4*)&Ksh[(row2 + 0) * KS + c4] = uk.v;
    uk.h[0] = pk2(k1.x, k1.y);
    uk.h[1] = pk2(k1.z, k1.w);
    *(f16x4*)&Ksh[(row2 + 1) * KS + c4] = uk.v;
    *(f16x2*)&Vsh[(c4 + 0) * VS + row2] = pk2(v0.x, v1.x);
    *(f16x2*)&Vsh[(c4 + 1) * VS + row2] = pk2(v0.y, v1.y);
    *(f16x2*)&Vsh[(c4 + 2) * VS + row2] = pk2(v0.z, v1.z);
    *(f16x2*)&Vsh[(c4 + 3) * VS + row2] = pk2(v0.w, v1.w);
}

__global__ __launch_bounds__(NTHREADS, 4)   // 4 waves/EU -> 2 blocks/CU guaranteed (VGPR<=128)
void swa_kernel(const float* __restrict__ qg, const float* __restrict__ kg,
                const float* __restrict__ vg, float* __restrict__ outg) {
    // double-buffered staging: buf[i] = { Ksh [BN][KS] f16 | Vsh [DIM][VS] f16 }
    // epilogue: Osh f32 [BM][OS] overlays both buffers
    __shared__ __align__(16) char smem[SMEMBYTES];
    float* Osh = (float*)smem;

    const int tid  = threadIdx.x;
    const int lane = tid & 63;
    const int wave = tid >> 6;     // 0..7
    const int lr   = lane & 15;
    const int quad = lane >> 4;

    // ---- chunked XCD swizzle: cluster 4 CONSECUTIVE qblks of one batch on one
    // XCD (their key windows overlap by 512/640 keys -> L2-served KV refetch).
    // HW round-robins flattened block id over 8 XCDs; members of a chunk sit in
    // adjacent dispatch slots of the same XCD round, so they are co-resident.
    static_assert(SEQ / BM == 32 && BATCH == 16, "swizzle assumes 512 blocks");
    const int lin    = blockIdx.x + (SEQ / BM) * blockIdx.y;  // 0..511
    const int xcd    = lin & 7;
    const int slot   = lin >> 3;          // 0..63 (per-XCD slot)
    const int member = slot & 3;          // position within chunk
    const int gchunk = (slot >> 2) * 8 + xcd;  // 0..127, bijective
    const int b      = gchunk >> 3;            // 16 batches
    const int qblk   = (gchunk & 7) * 4 + member;  // 32 qblks

    const int qrow0 = qblk * BM;
    const int wr0   = qrow0 + wave * 16;
    const int q     = wr0 + lr;          // this lane's q column (S^T layout)

    const float* qb = qg + (size_t)b * SEQ * DIM;
    const float* kb = kg + (size_t)b * SEQ * DIM;
    const float* vb = vg + (size_t)b * SEQ * DIM;
    float*       ob = outg + (size_t)b * SEQ * DIM;

    // staging thread->slot map: two adjacent rows per thread
    const int row2 = (tid >> 4) * 2;      // 0,2,...,62
    const int c4   = (tid & 15) * 4;      // 0..60

    // ---- Q B-frags straight from global into registers ----
    const float* qp = qb + (size_t)q * DIM + quad * 8;
    const float4 a0 = *(const float4*)(qp + 0);
    const float4 a1 = *(const float4*)(qp + 4);
    const float4 a2 = *(const float4*)(qp + 32);
    const float4 a3 = *(const float4*)(qp + 36);
    union { f16x8 v; f16x2 h[4]; } uq0, uq1;
    uq0.h[0] = pk2(a0.x * QSCALE, a0.y * QSCALE);
    uq0.h[1] = pk2(a0.z * QSCALE, a0.w * QSCALE);
    uq0.h[2] = pk2(a1.x * QSCALE, a1.y * QSCALE);
    uq0.h[3] = pk2(a1.z * QSCALE, a1.w * QSCALE);
    uq1.h[0] = pk2(a2.x * QSCALE, a2.y * QSCALE);
    uq1.h[1] = pk2(a2.z * QSCALE, a2.w * QSCALE);
    uq1.h[2] = pk2(a3.x * QSCALE, a3.y * QSCALE);
    uq1.h[3] = pk2(a3.z * QSCALE, a3.w * QSCALE);
    const f16x8 qf0 = uq0.v, qf1 = uq1.v;

    f32x4 o[4];
    #pragma unroll
    for (int mi = 0; mi < 4; ++mi) o[mi] = (f32x4){0.f, 0.f, 0.f, 0.f};
    float m_run = -1e30f, l_run = 0.f;

    const int t0 = (qrow0 > (WIN - 1)) ? (qrow0 - (WIN - 1)) >> 6 : 0;
    const int t1 = (qrow0 + BM - 1) >> 6;

    // ---- prologue: stage tile t0 into buffer 0 ----
    {
        const size_t g0 = (size_t)(t0 * BN + row2) * DIM + c4;
        const float4 k0 = *(const float4*)&kb[g0];
        const float4 v0 = *(const float4*)&vb[g0];
        const float4 k1 = *(const float4*)&kb[g0 + DIM];
        const float4 v1 = *(const float4*)&vb[g0 + DIM];
        stage_kv2((_Float16*)smem, (_Float16*)(smem + KBYTES), k0, k1, v0, v1, row2, c4);
    }
    __syncthreads();

    for (int t = t0; t <= t1; ++t) {
        const int cb = (t - t0) & 1;
        const _Float16* Kc = (const _Float16*)(smem + cb * BUFBYTES);
        const _Float16* Vc = (const _Float16*)(smem + cb * BUFBYTES + KBYTES);
        const bool have_next = (t < t1);

        float4 kp0, kp1, vp0, vp1;
        if (have_next) {
            // issue next tile's global loads NOW; staged after compute so the
            // HBM/L2 latency hides under this tile's MFMA+softmax
            const size_t g0 = (size_t)((t + 1) * BN + row2) * DIM + c4;
            kp0 = *(const float4*)&kb[g0];
            vp0 = *(const float4*)&vb[g0];
            kp1 = *(const float4*)&kb[g0 + DIM];
            vp1 = *(const float4*)&vb[g0 + DIM];
        }

        const int kbase = t * BN;
        // wave-level skip: no key of this tile is inside this wave's window
        const bool active = (kbase + BN - 1 >= wr0 - (WIN - 1)) && (kbase <= wr0 + 15);
        if (active) {
            // ---- S^T = K * Q^T : 4 key m-tiles x 2 k-chunks of 32 ----
            f32x4 sc[4];
            #pragma unroll
            for (int mt = 0; mt < 4; ++mt) {
                const f16x8 kf0 = *(const f16x8*)&Kc[(mt * 16 + lr) * KS + quad * 8];
                const f16x8 kf1 = *(const f16x8*)&Kc[(mt * 16 + lr) * KS + 32 + quad * 8];
                f32x4 s = (f32x4){0.f, 0.f, 0.f, 0.f};
                s = __builtin_amdgcn_mfma_f32_16x16x32_f16(kf0, qf0, s, 0, 0, 0);
                s = __builtin_amdgcn_mfma_f32_16x16x32_f16(kf1, qf1, s, 0, 0, 0);
                sc[mt] = s;
            }

            // ---- mask only on window-edge tiles (wave-uniform branch) ----
            const bool edge = (kbase < wr0 + 15 - (WIN - 1)) || (kbase + BN - 1 > wr0);
            if (edge) {
                #pragma unroll
                for (int mt = 0; mt < 4; ++mt) {
                    #pragma unroll
                    for (int r = 0; r < 4; ++r) {
                        const int key = kbase + mt * 16 + quad * 4 + r;
                        sc[mt][r] = ((unsigned)(q - key) < (unsigned)WIN) ? sc[mt][r] : MASKVAL;
                    }
                }
            }

            // ---- row max: balanced tree (fuses to v_max3), then cross-quad ----
            const float pmA = fmaxf(fmaxf(sc[0][0], sc[0][1]), fmaxf(sc[0][2], sc[0][3]));
            const float pmB = fmaxf(fmaxf(sc[1][0], sc[1][1]), fmaxf(sc[1][2], sc[1][3]));
            const float pmC = fmaxf(fmaxf(sc[2][0], sc[2][1]), fmaxf(sc[2][2], sc[2][3]));
            const float pmD = fmaxf(fmaxf(sc[3][0], sc[3][1]), fmaxf(sc[3][2], sc[3][3]));
            float pm = fmaxf(fmaxf(pmA, pmB), fmaxf(pmC, pmD));
            pm = fmaxf(pm, __shfl_xor(pm, 16));
            pm = fmaxf(pm, __shfl_xor(pm, 32));

            // ---- T13 defer-rescale: only rescale when max grew by > THR ----
            if (__any(pm > m_run + DEFER_THR)) {
                const float mn    = fmaxf(m_run, pm);
                const float alpha = exp2f(m_run - mn);
                m_run = mn;
                l_run *= alpha;
                #pragma unroll
                for (int mi = 0; mi < 4; ++mi) o[mi] = o[mi] * alpha;
            }

            f16x4 pb[4];
            float ls = 0.f;
            #pragma unroll
            for (int nt = 0; nt < 4; ++nt) {
                const float p0 = exp2f(sc[nt][0] - m_run);
                const float p1 = exp2f(sc[nt][1] - m_run);
                const float p2 = exp2f(sc[nt][2] - m_run);
                const float p3 = exp2f(sc[nt][3] - m_run);
                ls += (p0 + p1) + (p2 + p3);
                union { f16x4 v; f16x2 h[2]; } up;
                up.h[0] = pk2(p0, p1);
                up.h[1] = pk2(p2, p3);
                pb[nt] = up.v;
            }
            l_run += ls;

            // ---- O^T += V^T * P^T : P^T (C-layout) is the B-operand of 16x16x16 ----
            #pragma unroll
            for (int nt = 0; nt < 4; ++nt) {
                #pragma unroll
                for (int mi = 0; mi < 4; ++mi) {
                    const f16x4 vf = *(const f16x4*)&Vc[(mi * 16 + lr) * VS + nt * 16 + quad * 4];
                    o[mi] = __builtin_amdgcn_mfma_f32_16x16x16f16(vf, pb[nt], o[mi], 0, 0, 0);
                }
            }
        }

        // ---- stage t+1 into the ALTERNATE buffer; one barrier per tile ----
        if (have_next) {
            _Float16* Kn = (_Float16*)(smem + (cb ^ 1) * BUFBYTES);
            _Float16* Vn = (_Float16*)(smem + (cb ^ 1) * BUFBYTES + KBYTES);
            stage_kv2(Kn, Vn, kp0, kp1, vp0, vp1, row2, c4);
        }
        __syncthreads();
    }

    // ---- epilogue: l reduce across quads, normalize, transpose via LDS, store ----
    l_run += __shfl_xor(l_run, 16);
    l_run += __shfl_xor(l_run, 32);
    const float inv = 1.0f / l_run;

    float* Ow = Osh + wave * 16 * OS;   // per-wave private 16 x OS region
    #pragma unroll
    for (int mi = 0; mi < 4; ++mi) {
        float4 st;
        st.x = o[mi][0] * inv; st.y = o[mi][1] * inv;
        st.z = o[mi][2] * inv; st.w = o[mi][3] * inv;
        *(float4*)&Ow[lr * OS + mi * 16 + quad * 4] = st;
    }
    #pragma unroll
    for (int j = 0; j < 4; ++j) {
        const int qq = quad + 4 * j;
        const int d4 = lr * 4;
        const float4 vst = *(const float4*)&Ow[qq * OS + d4];
        *(float4*)&ob[(size_t)(wr0 + qq) * DIM + d4] = vst;
    }
}

extern "C" void kernel_launch(void* const* d_in, const int* in_sizes, int n_in,
                              void* d_out, int out_size, void* d_ws, size_t ws_size,
                              hipStream_t stream) {
    (void)in_sizes; (void)n_in; (void)out_size; (void)d_ws; (void)ws_size;
    const float* q = (const float*)d_in[0];
    const float* k = (const float*)d_in[1];
    const float* v = (const float*)d_in[2];
    float* out = (float*)d_out;
    dim3 grid(SEQ / BM, BATCH);
    swa_kernel<<<grid, dim3(NTHREADS), 0, stream>>>(q, k, v, out);
}